// Round 12
// baseline (317.412 us; speedup 1.0000x reference)
//
#include <hip/hip_runtime.h>
#include <stdint.h>

#define BATCH 2
#define SEQ   2048
#define DIM   1024
#define NH    16
#define DH    64

typedef short bf16x8 __attribute__((ext_vector_type(8)));
typedef float floatx4 __attribute__((ext_vector_type(4)));

__device__ __forceinline__ int swz(int r) { return (r ^ (r >> 2)) & 3; }

// fast 2^x: raw v_exp_f32
#if __has_builtin(__builtin_amdgcn_exp2f)
#define EXP2(x) __builtin_amdgcn_exp2f(x)
#else
#define EXP2(x) __expf((x) * 0.6931471805599453f)
#endif

__device__ __forceinline__ uint32_t pack_bf16_rne(float x0, float x1) {
    uint32_t u0 = __float_as_uint(x0), u1 = __float_as_uint(x1);
    u0 += 0x7FFFu + ((u0 >> 16) & 1);
    u1 += 0x7FFFu + ((u1 >> 16) & 1);
    return (u0 >> 16) | (u1 & 0xFFFF0000u);
}

__device__ __forceinline__ ushort bf16_rne1(float x) {
    uint32_t u = __float_as_uint(x);
    u += 0x7FFFu + ((u >> 16) & 1);
    return (ushort)(u >> 16);
}

// softmax scale folded into K: 0.125 * log2(e) -> flash uses exp2
#define KSCALE 0.18033688011112042f

// ---------------- fused qv+k projection GEMM: bf16, BK=64, XCD swizzle ------
// Default dispatch puts all 8 XCDs on the SAME A-panel (by) at once -> A
// fetched 8x (FETCH 147MB vs ~50 ideal). Bijective swizzle (768%8==0) gives
// each XCD its own by-range: A fetched once, B (small) 8x.
__global__ __launch_bounds__(256, 3)
void gemm_qvk(const float* __restrict__ Aqv, const float* __restrict__ Akp,
              const float* __restrict__ Wqv, const float* __restrict__ Wkp,
              uint32_t* __restrict__ qh, ushort* __restrict__ vt,
              uint32_t* __restrict__ kh)
{
    __shared__ uint32_t Ah[2][128 * 16], Bh[2][128 * 16];

    const int t    = threadIdx.x;
    const int lane = t & 63;
    const int w    = t >> 6;
    const int wm   = w & 1, wn = w >> 1;
    const int quad = lane >> 4, l15 = lane & 15;

    // XCD-bijective block swizzle: each XCD gets 4 consecutive by-rows
    const int lin = blockIdx.y * 24 + blockIdx.x;
    const int sl  = (lin & 7) * 96 + (lin >> 3);
    const int bxs = sl % 24;
    const int bys = sl / 24;

    const bool is_qv = (bxs < 16);
    const float* Af = is_qv ? Aqv : Akp;
    const float* Bf = is_qv ? Wqv : Wkp;
    const int N    = is_qv ? 2048 : 1024;
    const int n0   = (is_qv ? bxs : bxs - 16) * 128;
    const int m0   = bys * 128;

    const int ar  = t >> 1;
    const int ab0 = (t & 1) * 2;
    const int as  = swz(ar);
    const int bc  = (t & 31) * 4;
    const int bk  = (t >> 5) * 4;
    const int bb  = bk >> 3;
    const int bp  = (bk & 7) >> 1;
    const bool nsel = ((bc >> 4) & 1) != 0;

    floatx4 acc[4][4];
    #pragma unroll
    for (int i = 0; i < 4; i++)
        #pragma unroll
        for (int j = 0; j < 4; j++)
            #pragma unroll
            for (int e = 0; e < 4; e++) acc[i][j][e] = 0.0f;

    // prefetch registers, static indexing only (scratch hazard otherwise)
    float f0[16], f1[16];
    float4 g40[4], g41[4];
    {
        #pragma unroll
        for (int i = 0; i < 4; i++) {
            *(float4*)&f0[i * 4] =
                *(const float4*)&Af[(size_t)(m0 + ar) * 1024 + ab0 * 8 + i * 4];
            *(float4*)&f1[i * 4] =
                *(const float4*)&Af[(size_t)(m0 + ar) * 1024 + 32 + ab0 * 8 + i * 4];
        }
        #pragma unroll
        for (int j = 0; j < 4; j++) {
            g40[j] = *(const float4*)&Bf[(size_t)(bk + j) * N + n0 + bc];
            g41[j] = *(const float4*)&Bf[(size_t)(32 + bk + j) * N + n0 + bc];
        }
    }

    for (int k0 = 0; k0 < 1024; k0 += 64) {
        if (k0) __syncthreads();
        // ---- stage A halves (bf16-rne pack) ----
        {
            uint32_t hi[8];
            #pragma unroll
            for (int j = 0; j < 8; j++) hi[j] = pack_bf16_rne(f0[2 * j], f0[2 * j + 1]);
            int i0 = ar * 16 + ((ab0 ^ as) * 4);
            int i1 = ar * 16 + (((ab0 + 1) ^ as) * 4);
            *(uint4*)&Ah[0][i0] = make_uint4(hi[0], hi[1], hi[2], hi[3]);
            *(uint4*)&Ah[0][i1] = make_uint4(hi[4], hi[5], hi[6], hi[7]);
            #pragma unroll
            for (int j = 0; j < 8; j++) hi[j] = pack_bf16_rne(f1[2 * j], f1[2 * j + 1]);
            *(uint4*)&Ah[1][i0] = make_uint4(hi[0], hi[1], hi[2], hi[3]);
            *(uint4*)&Ah[1][i1] = make_uint4(hi[4], hi[5], hi[6], hi[7]);
        }
        // ---- stage B halves (conflict-min order, static extracts) ----
        {
            #pragma unroll
            for (int i = 0; i < 4; i++) {
                int n = bc + (i ^ (nsel ? 1 : 0));
                int bi = n * 16 + ((bb ^ swz(n)) * 4) + bp;
                float e0 = nsel ? ((const float*)&g40[0])[i ^ 1] : ((const float*)&g40[0])[i];
                float e1 = nsel ? ((const float*)&g40[1])[i ^ 1] : ((const float*)&g40[1])[i];
                float e2 = nsel ? ((const float*)&g40[2])[i ^ 1] : ((const float*)&g40[2])[i];
                float e3 = nsel ? ((const float*)&g40[3])[i ^ 1] : ((const float*)&g40[3])[i];
                *(uint2*)&Bh[0][bi] = make_uint2(pack_bf16_rne(e0, e1), pack_bf16_rne(e2, e3));
                e0 = nsel ? ((const float*)&g41[0])[i ^ 1] : ((const float*)&g41[0])[i];
                e1 = nsel ? ((const float*)&g41[1])[i ^ 1] : ((const float*)&g41[1])[i];
                e2 = nsel ? ((const float*)&g41[2])[i ^ 1] : ((const float*)&g41[2])[i];
                e3 = nsel ? ((const float*)&g41[3])[i ^ 1] : ((const float*)&g41[3])[i];
                *(uint2*)&Bh[1][bi] = make_uint2(pack_bf16_rne(e0, e1), pack_bf16_rne(e2, e3));
            }
        }
        __syncthreads();

        // ---- prefetch next BK=64 step ----
        if (k0 + 64 < 1024) {
            #pragma unroll
            for (int i = 0; i < 4; i++) {
                *(float4*)&f0[i * 4] =
                    *(const float4*)&Af[(size_t)(m0 + ar) * 1024 + (k0 + 64) + ab0 * 8 + i * 4];
                *(float4*)&f1[i * 4] =
                    *(const float4*)&Af[(size_t)(m0 + ar) * 1024 + (k0 + 96) + ab0 * 8 + i * 4];
            }
            #pragma unroll
            for (int j = 0; j < 4; j++) {
                g40[j] = *(const float4*)&Bf[(size_t)(k0 + 64 + bk + j) * N + n0 + bc];
                g41[j] = *(const float4*)&Bf[(size_t)(k0 + 96 + bk + j) * N + n0 + bc];
            }
        }

        #pragma unroll
        for (int half = 0; half < 2; half++) {
            bf16x8 vb[4];
            #pragma unroll
            for (int fn = 0; fn < 4; fn++) {
                int br = wn * 64 + fn * 16 + l15;
                int bi = br * 16 + ((quad ^ swz(br)) * 4);
                vb[fn] = *(const bf16x8*)&Bh[half][bi];
            }
            #pragma unroll
            for (int fm = 0; fm < 4; fm++) {
                int arow = wm * 64 + fm * 16 + l15;
                int ai = arow * 16 + ((quad ^ swz(arow)) * 4);
                bf16x8 va = *(const bf16x8*)&Ah[half][ai];
                #pragma unroll
                for (int fn = 0; fn < 4; fn++)
                    acc[fm][fn] = __builtin_amdgcn_mfma_f32_16x16x32_bf16(vb[fn], va, acc[fm][fn], 0, 0, 0);
            }
        }
    }

    #pragma unroll
    for (int fm = 0; fm < 4; fm++) {
        int row = m0 + wm * 64 + fm * 16 + l15;
        #pragma unroll
        for (int fn = 0; fn < 4; fn++) {
            int colb = n0 + wn * 64 + fn * 16 + quad * 4;
            floatx4 a = acc[fm][fn];
            if (is_qv) {
                if (colb < 1024) {
                    uint32_t u0 = pack_bf16_rne(a[0], a[1]);
                    uint32_t u1 = pack_bf16_rne(a[2], a[3]);
                    size_t wi = (size_t)row * 512 + (colb >> 1);
                    *(uint2*)&qh[wi] = make_uint2(u0, u1);
                } else {
                    // V transposed: vt[h][d][token] bf16
                    int hh = (colb - 1024) >> 6;
                    int d0 = (colb - 1024) & 63;
                    #pragma unroll
                    for (int j = 0; j < 4; j++)
                        vt[(size_t)(hh * 64 + d0 + j) * 4096 + row] = bf16_rne1(a[j]);
                }
            } else {
                uint32_t u0 = pack_bf16_rne(a[0] * KSCALE, a[1] * KSCALE);
                uint32_t u1 = pack_bf16_rne(a[2] * KSCALE, a[3] * KSCALE);
                size_t wi = (size_t)row * 512 + (colb >> 1);
                *(uint2*)&kh[wi] = make_uint2(u0, u1);
            }
        }
    }
}

// ---------------- proj GEMM: bf16, split-K=2, BK=64, XCD swizzle ------------
__global__ __launch_bounds__(256, 3)
void gemm_projB(const uint32_t* __restrict__ Ag,
                const float* __restrict__ Bf, const float* __restrict__ bias,
                float* __restrict__ Cf, float* __restrict__ P1)
{
    __shared__ uint32_t Ah[2][128 * 16], Bh[2][128 * 16];

    const int t    = threadIdx.x;
    const int lane = t & 63;
    const int w    = t >> 6;
    const int wm   = w & 1, wn = w >> 1;
    const int quad = lane >> 4, l15 = lane & 15;

    // XCD-bijective block swizzle (512 % 8 == 0)
    const int lin = blockIdx.z * 256 + blockIdx.y * 8 + blockIdx.x;
    const int sl  = (lin & 7) * 64 + (lin >> 3);
    const int bxs = sl & 7;
    const int bys = (sl >> 3) & 31;
    const int kz  = sl >> 8;

    const int m0 = bys * 128, n0 = bxs * 128;
    const int k0 = kz * 512;
    const int N  = 1024;

    const int bc  = (t & 31) * 4;
    const int bk  = (t >> 5) * 4;
    const int bb  = bk >> 3;
    const int bp  = (bk & 7) >> 1;
    const bool nsel = ((bc >> 4) & 1) != 0;

    const int arow0 = t >> 2, akbl = t & 3;
    const int arow1 = (t + 256) >> 2;
    const int dst0 = arow0 * 16 + ((akbl ^ swz(arow0)) * 4);
    const int dst1 = arow1 * 16 + ((akbl ^ swz(arow1)) * 4);

    floatx4 acc[4][4];
    #pragma unroll
    for (int i = 0; i < 4; i++)
        #pragma unroll
        for (int j = 0; j < 4; j++)
            #pragma unroll
            for (int e = 0; e < 4; e++) acc[i][j][e] = 0.0f;

    uint4 gA00, gA01, gA10, gA11;
    float4 g40[4], g41[4];
    {
        size_t s0 = (size_t)(m0 + arow0) * 512 + (k0 >> 1) + akbl * 4;
        size_t s1 = (size_t)(m0 + arow1) * 512 + (k0 >> 1) + akbl * 4;
        gA00 = *(const uint4*)&Ag[s0];
        gA01 = *(const uint4*)&Ag[s1];
        gA10 = *(const uint4*)&Ag[s0 + 16];
        gA11 = *(const uint4*)&Ag[s1 + 16];
        #pragma unroll
        for (int j = 0; j < 4; j++) {
            g40[j] = *(const float4*)&Bf[(size_t)(k0 + bk + j) * N + n0 + bc];
            g41[j] = *(const float4*)&Bf[(size_t)(k0 + 32 + bk + j) * N + n0 + bc];
        }
    }

    for (int kk = 0; kk < 512; kk += 64) {
        if (kk) __syncthreads();
        {
            *(uint4*)&Ah[0][dst0] = gA00;
            *(uint4*)&Ah[0][dst1] = gA01;
            *(uint4*)&Ah[1][dst0] = gA10;
            *(uint4*)&Ah[1][dst1] = gA11;
        }
        {
            #pragma unroll
            for (int i = 0; i < 4; i++) {
                int n = bc + (i ^ (nsel ? 1 : 0));
                int bi = n * 16 + ((bb ^ swz(n)) * 4) + bp;
                float e0 = nsel ? ((const float*)&g40[0])[i ^ 1] : ((const float*)&g40[0])[i];
                float e1 = nsel ? ((const float*)&g40[1])[i ^ 1] : ((const float*)&g40[1])[i];
                float e2 = nsel ? ((const float*)&g40[2])[i ^ 1] : ((const float*)&g40[2])[i];
                float e3 = nsel ? ((const float*)&g40[3])[i ^ 1] : ((const float*)&g40[3])[i];
                *(uint2*)&Bh[0][bi] = make_uint2(pack_bf16_rne(e0, e1), pack_bf16_rne(e2, e3));
                e0 = nsel ? ((const float*)&g41[0])[i ^ 1] : ((const float*)&g41[0])[i];
                e1 = nsel ? ((const float*)&g41[1])[i ^ 1] : ((const float*)&g41[1])[i];
                e2 = nsel ? ((const float*)&g41[2])[i ^ 1] : ((const float*)&g41[2])[i];
                e3 = nsel ? ((const float*)&g41[3])[i ^ 1] : ((const float*)&g41[3])[i];
                *(uint2*)&Bh[1][bi] = make_uint2(pack_bf16_rne(e0, e1), pack_bf16_rne(e2, e3));
            }
        }
        __syncthreads();

        if (kk + 64 < 512) {
            const int kg = k0 + kk + 64;
            size_t s0 = (size_t)(m0 + arow0) * 512 + (kg >> 1) + akbl * 4;
            size_t s1 = (size_t)(m0 + arow1) * 512 + (kg >> 1) + akbl * 4;
            gA00 = *(const uint4*)&Ag[s0];
            gA01 = *(const uint4*)&Ag[s1];
            gA10 = *(const uint4*)&Ag[s0 + 16];
            gA11 = *(const uint4*)&Ag[s1 + 16];
            #pragma unroll
            for (int j = 0; j < 4; j++) {
                g40[j] = *(const float4*)&Bf[(size_t)(kg + bk + j) * N + n0 + bc];
                g41[j] = *(const float4*)&Bf[(size_t)(kg + 32 + bk + j) * N + n0 + bc];
            }
        }

        #pragma unroll
        for (int half = 0; half < 2; half++) {
            bf16x8 vb[4];
            #pragma unroll
            for (int fn = 0; fn < 4; fn++) {
                int br = wn * 64 + fn * 16 + l15;
                int bi = br * 16 + ((quad ^ swz(br)) * 4);
                vb[fn] = *(const bf16x8*)&Bh[half][bi];
            }
            #pragma unroll
            for (int fm = 0; fm < 4; fm++) {
                int arow = wm * 64 + fm * 16 + l15;
                int ai = arow * 16 + ((quad ^ swz(arow)) * 4);
                bf16x8 va = *(const bf16x8*)&Ah[half][ai];
                #pragma unroll
                for (int fn = 0; fn < 4; fn++)
                    acc[fm][fn] = __builtin_amdgcn_mfma_f32_16x16x32_bf16(vb[fn], va, acc[fm][fn], 0, 0, 0);
            }
        }
    }

    #pragma unroll
    for (int fm = 0; fm < 4; fm++) {
        int row = m0 + wm * 64 + fm * 16 + l15;
        #pragma unroll
        for (int fn = 0; fn < 4; fn++) {
            int colb = n0 + wn * 64 + fn * 16 + quad * 4;
            floatx4 a = acc[fm][fn];
            float4 v;
            if (kz == 0) {
                float4 bb4 = *(const float4*)&bias[colb];
                v.x = a[0] + bb4.x; v.y = a[1] + bb4.y;
                v.z = a[2] + bb4.z; v.w = a[3] + bb4.w;
                *(float4*)&Cf[(size_t)row * N + colb] = v;
            } else {
                v.x = a[0]; v.y = a[1]; v.z = a[2]; v.w = a[3];
                *(float4*)&P1[(size_t)row * N + colb] = v;
            }
        }
    }
}

// ---------------- combine: out += partial1 (L2/L3-resident) -----------------
__global__ __launch_bounds__(256)
void add_partial(const float4* __restrict__ p1, float4* __restrict__ out, int n4)
{
    int i = blockIdx.x * 256 + threadIdx.x;
    int stride = gridDim.x * 256;
    for (; i < n4; i += stride) {
        float4 a = out[i];
        float4 b = p1[i];
        a.x += b.x; a.y += b.y; a.z += b.z; a.w += b.w;
        out[i] = a;
    }
}

// ---------------- MFMA flash attention: KVBLK=128, V direct from L2 ---------
// V per (b,h) = 256 KB, L2-resident: staging it in LDS was pure overhead
// (guide common-mistake #7). Dropping Vt -> LDS 51.2 KB -> 3 blocks/CU
// (12 waves/CU) for latency hiding; V fragments read straight from global.
#define FST 34   // Kh row stride (32 words + 2 pad)
#define FSP 66   // Pt row stride (64 words + 2 pad)
#define NT  (SEQ / 128)
__global__ __launch_bounds__(256, 3)
void flash_attn(const uint32_t* __restrict__ qhg,
                const uint32_t* __restrict__ khg,
                const uint32_t* __restrict__ vtg,
                uint32_t* __restrict__ xhg)
{
    __shared__ uint32_t Kh[128 * FST];   // 17.4 KB
    __shared__ uint32_t Pt[128 * FSP];   // 33.8 KB  -> 51.2 KB total, 3/CU

    const int t    = threadIdx.x;
    const int lane = t & 63;
    const int w    = t >> 6;
    const int quad = lane >> 4, l15 = lane & 15;
    const int qb = blockIdx.x;
    const int h  = blockIdx.y;
    const int b  = blockIdx.z;

    const size_t rowbase = (size_t)b * SEQ;

    // ---- Q fragments (bf16-rne): load once, keep in registers ----
    bf16x8 vq[2][2];     // [s][nf]
    {
        #pragma unroll
        for (int nf = 0; nf < 2; nf++) {
            size_t row = rowbase + qb * 128 + w * 32 + nf * 16 + l15;
            size_t gw = row * 512 + h * 32 + quad * 4;
            #pragma unroll
            for (int s = 0; s < 2; s++)
                vq[s][nf] = *(const bf16x8*)&qhg[gw + s * 16];
        }
    }

    // ---- K staging coords + tile kt=0 prefetch ----
    const int kr  = t >> 1, kc0 = (t & 1) * 16;
    uint4 pk0, pk1, pk2, pk3;
    {
        size_t gw = (rowbase + kr) * 512 + h * 32 + kc0;
        pk0 = *(const uint4*)&khg[gw];
        pk1 = *(const uint4*)&khg[gw + 4];
        pk2 = *(const uint4*)&khg[gw + 8];
        pk3 = *(const uint4*)&khg[gw + 12];
    }

    // ---- per-lane V base (direct global reads in PV) ----
    const size_t vbl = (size_t)(h * 64 + l15) * 2048 + (rowbase >> 1) + quad * 4;

    float m_i[2] = {-INFINITY, -INFINITY};
    float l_i[2] = {0.0f, 0.0f};
    floatx4 acc_o[2][4];
    #pragma unroll
    for (int nf = 0; nf < 2; nf++)
        #pragma unroll
        for (int fm = 0; fm < 4; fm++)
            #pragma unroll
            for (int e = 0; e < 4; e++) acc_o[nf][fm][e] = 0.0f;

    for (int kt = 0; kt < NT; kt++) {
        __syncthreads();
        // ---- stage K from registers (4x uint4) ----
        {
            int kb0 = kr * FST + kc0;
            *(uint4*)&Kh[kb0]      = pk0;
            *(uint4*)&Kh[kb0 + 4]  = pk1;
            *(uint4*)&Kh[kb0 + 8]  = pk2;
            *(uint4*)&Kh[kb0 + 12] = pk3;
        }
        __syncthreads();

        // ---- prefetch K tile kt+1 (completes during compute) ----
        if (kt + 1 < NT) {
            size_t gw = (rowbase + (kt + 1) * 128 + kr) * 512 + h * 32 + kc0;
            pk0 = *(const uint4*)&khg[gw];
            pk1 = *(const uint4*)&khg[gw + 4];
            pk2 = *(const uint4*)&khg[gw + 8];
            pk3 = *(const uint4*)&khg[gw + 12];
        }

        // ---- S^T = rne(K)·rne(Q): 32 MFMAs over 128 k-rows ----
        floatx4 sacc[2][8];
        #pragma unroll
        for (int nf = 0; nf < 2; nf++)
            #pragma unroll
            for (int fm = 0; fm < 8; fm++)
                #pragma unroll
                for (int e = 0; e < 4; e++) sacc[nf][fm][e] = 0.0f;

        __builtin_amdgcn_s_setprio(1);
        #pragma unroll
        for (int s = 0; s < 2; s++) {
            #pragma unroll
            for (int fm = 0; fm < 8; fm++) {
                int ki = (fm * 16 + l15) * FST + s * 16 + quad * 4;
                bf16x8 vk = *(const bf16x8*)&Kh[ki];
                #pragma unroll
                for (int nf = 0; nf < 2; nf++)
                    sacc[nf][fm] = __builtin_amdgcn_mfma_f32_16x16x32_bf16(vk, vq[s][nf], sacc[nf][fm], 0, 0, 0);
            }
        }
        __builtin_amdgcn_s_setprio(0);

        // ---- online softmax (in-place on sacc; defer-max THR=8) ----
        #pragma unroll
        for (int nf = 0; nf < 2; nf++) {
            float mt = -INFINITY;
            #pragma unroll
            for (int fm = 0; fm < 8; fm++)
                #pragma unroll
                for (int r = 0; r < 4; r++) mt = fmaxf(mt, sacc[nf][fm][r]);
            mt = fmaxf(mt, __shfl_xor(mt, 16));
            mt = fmaxf(mt, __shfl_xor(mt, 32));

            if (__all(mt - m_i[nf] <= 8.0f)) {
                float rs = 0.0f;
                #pragma unroll
                for (int fm = 0; fm < 8; fm++)
                    #pragma unroll
                    for (int r = 0; r < 4; r++) {
                        sacc[nf][fm][r] = EXP2(sacc[nf][fm][r] - m_i[nf]);
                        rs += sacc[nf][fm][r];
                    }
                rs += __shfl_xor(rs, 16);
                rs += __shfl_xor(rs, 32);
                l_i[nf] += rs;
            } else {
                float m_new = fmaxf(m_i[nf], mt);
                float alpha = EXP2(m_i[nf] - m_new);
                float rs = 0.0f;
                #pragma unroll
                for (int fm = 0; fm < 8; fm++)
                    #pragma unroll
                    for (int r = 0; r < 4; r++) {
                        sacc[nf][fm][r] = EXP2(sacc[nf][fm][r] - m_new);
                        rs += sacc[nf][fm][r];
                    }
                rs += __shfl_xor(rs, 16);
                rs += __shfl_xor(rs, 32);
                l_i[nf] = l_i[nf] * alpha + rs;
                m_i[nf] = m_new;
                #pragma unroll
                for (int fm = 0; fm < 4; fm++)
                    #pragma unroll
                    for (int e = 0; e < 4; e++) acc_o[nf][fm][e] *= alpha;
            }

            int qrow = w * 32 + nf * 16 + l15;
            #pragma unroll
            for (int fm = 0; fm < 8; fm++) {
                uint32_t u0 = pack_bf16_rne(sacc[nf][fm][0], sacc[nf][fm][1]);
                uint32_t u1 = pack_bf16_rne(sacc[nf][fm][2], sacc[nf][fm][3]);
                *(uint2*)&Pt[qrow * FSP + fm * 8 + quad * 2] = make_uint2(u0, u1);
            }
        }

        // ---- O^T += V · P^T (V fragments direct from global/L2) ----
        __builtin_amdgcn_s_setprio(1);
        #pragma unroll
        for (int s = 0; s < 4; s++) {
            bf16x8 pb[2];
            #pragma unroll
            for (int nf = 0; nf < 2; nf++)
                pb[nf] = *(const bf16x8*)&Pt[(w * 32 + nf * 16 + l15) * FSP + s * 16 + quad * 4];
            #pragma unroll
            for (int fm = 0; fm < 4; fm++) {
                bf16x8 va = *(const bf16x8*)&vtg[vbl + (size_t)fm * 32768 + kt * 64 + s * 16];
                #pragma unroll
                for (int nf = 0; nf < 2; nf++)
                    acc_o[nf][fm] = __builtin_amdgcn_mfma_f32_16x16x32_bf16(va, pb[nf], acc_o[nf][fm], 0, 0, 0);
            }
        }
        __builtin_amdgcn_s_setprio(0);
    }

    // ---- epilogue: write x single bf16-rne ----
    #pragma unroll
    for (int nf = 0; nf < 2; nf++) {
        float rl = 1.0f / l_i[nf];
        size_t row = rowbase + qb * 128 + w * 32 + nf * 16 + l15;
        #pragma unroll
        for (int fm = 0; fm < 4; fm++) {
            int d0 = fm * 16 + quad * 4;
            uint32_t u0 = pack_bf16_rne(acc_o[nf][fm][0] * rl, acc_o[nf][fm][1] * rl);
            uint32_t u1 = pack_bf16_rne(acc_o[nf][fm][2] * rl, acc_o[nf][fm][3] * rl);
            size_t wi = row * 512 + ((h * 64 + d0) >> 1);
            *(uint2*)&xhg[wi] = make_uint2(u0, u1);
        }
    }
}

extern "C" void kernel_launch(void* const* d_in, const int* in_sizes, int n_in,
                              void* d_out, int out_size, void* d_ws, size_t ws_size,
                              hipStream_t stream)
{
    const float* input_qv = (const float*)d_in[0];
    const float* input_k  = (const float*)d_in[1];
    const float* W_qv     = (const float*)d_in[2];
    const float* W_k      = (const float*)d_in[3];
    const float* W_proj   = (const float*)d_in[4];
    const float* b_proj   = (const float*)d_in[5];
    float* out = (float*)d_out;

    const size_t RW = 4096 * 512;            // words per [4096][1024-bf16] buffer
    uint32_t* qh = (uint32_t*)d_ws;          // 3 RW = 25.2 MB total
    uint32_t* vt = qh + RW;                  // V^T [16 h][64 d][4096 tok] bf16
    uint32_t* xh = vt + RW;                  // attention out, single bf16
    uint32_t* kh = (uint32_t*)d_out;         // rne K parked in d_out (8.4 MB);
                                             // proj GEMM rewrites out afterwards
    float* p1 = (float*)d_ws;                // split-K partial: aliases qh+vt
                                             // (dead after flash_attn), 16.8 MB

    dim3 blk(256);
    // fused qv+k projections: 768 blocks, XCD-swizzled
    gemm_qvk<<<dim3(24, 32), blk, 0, stream>>>(
        input_qv, input_k, W_qv, W_k, qh, (ushort*)vt, kh);
    // flash attention: KVBLK=128, V direct from L2, 3 blocks/CU
    flash_attn<<<dim3(SEQ / 128, NH, BATCH), blk, 0, stream>>>(
        qh, kh, vt, xh);
    // output projection + bias: bf16, split-K=2, XCD-swizzled
    gemm_projB<<<dim3(8, 32, 2), blk, 0, stream>>>(
        xh, W_proj, b_proj, out, p1);
    // out += partial1
    add_partial<<<dim3(2048), blk, 0, stream>>>(
        (const float4*)p1, (float4*)out, 4096 * 1024 / 4);
}

// Round 13
// 260.106 us; speedup vs baseline: 1.2203x; 1.2203x over previous
//
#include <hip/hip_runtime.h>
#include <stdint.h>

#define BATCH 2
#define SEQ   2048
#define DIM   1024
#define NH    16
#define DH    64

typedef short bf16x8 __attribute__((ext_vector_type(8)));
typedef float floatx4 __attribute__((ext_vector_type(4)));

__device__ __forceinline__ int swz(int r) { return (r ^ (r >> 2)) & 3; }

// fast 2^x: raw v_exp_f32
#if __has_builtin(__builtin_amdgcn_exp2f)
#define EXP2(x) __builtin_amdgcn_exp2f(x)
#else
#define EXP2(x) __expf((x) * 0.6931471805599453f)
#endif

__device__ __forceinline__ uint32_t pack_bf16_rne(float x0, float x1) {
    uint32_t u0 = __float_as_uint(x0), u1 = __float_as_uint(x1);
    u0 += 0x7FFFu + ((u0 >> 16) & 1);
    u1 += 0x7FFFu + ((u1 >> 16) & 1);
    return (u0 >> 16) | (u1 & 0xFFFF0000u);
}

__device__ __forceinline__ ushort bf16_rne1(float x) {
    uint32_t u = __float_as_uint(x);
    u += 0x7FFFu + ((u >> 16) & 1);
    return (ushort)(u >> 16);
}

// softmax scale folded into K: 0.125 * log2(e) -> flash uses exp2
#define KSCALE 0.18033688011112042f

// ---------------- fused qv+k projection GEMM: bf16, BK=64, XCD swizzle ------
__global__ __launch_bounds__(256, 3)
void gemm_qvk(const float* __restrict__ Aqv, const float* __restrict__ Akp,
              const float* __restrict__ Wqv, const float* __restrict__ Wkp,
              uint32_t* __restrict__ qh, ushort* __restrict__ vt,
              uint32_t* __restrict__ kh)
{
    __shared__ uint32_t Ah[2][128 * 16], Bh[2][128 * 16];

    const int t    = threadIdx.x;
    const int lane = t & 63;
    const int w    = t >> 6;
    const int wm   = w & 1, wn = w >> 1;
    const int quad = lane >> 4, l15 = lane & 15;

    // XCD-bijective block swizzle (768 % 8 == 0)
    const int lin = blockIdx.y * 24 + blockIdx.x;
    const int sl  = (lin & 7) * 96 + (lin >> 3);
    const int bxs = sl % 24;
    const int bys = sl / 24;

    const bool is_qv = (bxs < 16);
    const float* Af = is_qv ? Aqv : Akp;
    const float* Bf = is_qv ? Wqv : Wkp;
    const int N    = is_qv ? 2048 : 1024;
    const int n0   = (is_qv ? bxs : bxs - 16) * 128;
    const int m0   = bys * 128;

    const int ar  = t >> 1;
    const int ab0 = (t & 1) * 2;
    const int as  = swz(ar);
    const int bc  = (t & 31) * 4;
    const int bk  = (t >> 5) * 4;
    const int bb  = bk >> 3;
    const int bp  = (bk & 7) >> 1;
    const bool nsel = ((bc >> 4) & 1) != 0;

    floatx4 acc[4][4];
    #pragma unroll
    for (int i = 0; i < 4; i++)
        #pragma unroll
        for (int j = 0; j < 4; j++)
            #pragma unroll
            for (int e = 0; e < 4; e++) acc[i][j][e] = 0.0f;

    // prefetch registers, static indexing only (scratch hazard otherwise)
    float f0[16], f1[16];
    float4 g40[4], g41[4];
    {
        #pragma unroll
        for (int i = 0; i < 4; i++) {
            *(float4*)&f0[i * 4] =
                *(const float4*)&Af[(size_t)(m0 + ar) * 1024 + ab0 * 8 + i * 4];
            *(float4*)&f1[i * 4] =
                *(const float4*)&Af[(size_t)(m0 + ar) * 1024 + 32 + ab0 * 8 + i * 4];
        }
        #pragma unroll
        for (int j = 0; j < 4; j++) {
            g40[j] = *(const float4*)&Bf[(size_t)(bk + j) * N + n0 + bc];
            g41[j] = *(const float4*)&Bf[(size_t)(32 + bk + j) * N + n0 + bc];
        }
    }

    for (int k0 = 0; k0 < 1024; k0 += 64) {
        if (k0) __syncthreads();
        // ---- stage A halves (bf16-rne pack) ----
        {
            uint32_t hi[8];
            #pragma unroll
            for (int j = 0; j < 8; j++) hi[j] = pack_bf16_rne(f0[2 * j], f0[2 * j + 1]);
            int i0 = ar * 16 + ((ab0 ^ as) * 4);
            int i1 = ar * 16 + (((ab0 + 1) ^ as) * 4);
            *(uint4*)&Ah[0][i0] = make_uint4(hi[0], hi[1], hi[2], hi[3]);
            *(uint4*)&Ah[0][i1] = make_uint4(hi[4], hi[5], hi[6], hi[7]);
            #pragma unroll
            for (int j = 0; j < 8; j++) hi[j] = pack_bf16_rne(f1[2 * j], f1[2 * j + 1]);
            *(uint4*)&Ah[1][i0] = make_uint4(hi[0], hi[1], hi[2], hi[3]);
            *(uint4*)&Ah[1][i1] = make_uint4(hi[4], hi[5], hi[6], hi[7]);
        }
        // ---- stage B halves (conflict-min order, static extracts) ----
        {
            #pragma unroll
            for (int i = 0; i < 4; i++) {
                int n = bc + (i ^ (nsel ? 1 : 0));
                int bi = n * 16 + ((bb ^ swz(n)) * 4) + bp;
                float e0 = nsel ? ((const float*)&g40[0])[i ^ 1] : ((const float*)&g40[0])[i];
                float e1 = nsel ? ((const float*)&g40[1])[i ^ 1] : ((const float*)&g40[1])[i];
                float e2 = nsel ? ((const float*)&g40[2])[i ^ 1] : ((const float*)&g40[2])[i];
                float e3 = nsel ? ((const float*)&g40[3])[i ^ 1] : ((const float*)&g40[3])[i];
                *(uint2*)&Bh[0][bi] = make_uint2(pack_bf16_rne(e0, e1), pack_bf16_rne(e2, e3));
                e0 = nsel ? ((const float*)&g41[0])[i ^ 1] : ((const float*)&g41[0])[i];
                e1 = nsel ? ((const float*)&g41[1])[i ^ 1] : ((const float*)&g41[1])[i];
                e2 = nsel ? ((const float*)&g41[2])[i ^ 1] : ((const float*)&g41[2])[i];
                e3 = nsel ? ((const float*)&g41[3])[i ^ 1] : ((const float*)&g41[3])[i];
                *(uint2*)&Bh[1][bi] = make_uint2(pack_bf16_rne(e0, e1), pack_bf16_rne(e2, e3));
            }
        }
        __syncthreads();

        // ---- prefetch next BK=64 step ----
        if (k0 + 64 < 1024) {
            #pragma unroll
            for (int i = 0; i < 4; i++) {
                *(float4*)&f0[i * 4] =
                    *(const float4*)&Af[(size_t)(m0 + ar) * 1024 + (k0 + 64) + ab0 * 8 + i * 4];
                *(float4*)&f1[i * 4] =
                    *(const float4*)&Af[(size_t)(m0 + ar) * 1024 + (k0 + 96) + ab0 * 8 + i * 4];
            }
            #pragma unroll
            for (int j = 0; j < 4; j++) {
                g40[j] = *(const float4*)&Bf[(size_t)(k0 + 64 + bk + j) * N + n0 + bc];
                g41[j] = *(const float4*)&Bf[(size_t)(k0 + 96 + bk + j) * N + n0 + bc];
            }
        }

        #pragma unroll
        for (int half = 0; half < 2; half++) {
            bf16x8 vb[4];
            #pragma unroll
            for (int fn = 0; fn < 4; fn++) {
                int br = wn * 64 + fn * 16 + l15;
                int bi = br * 16 + ((quad ^ swz(br)) * 4);
                vb[fn] = *(const bf16x8*)&Bh[half][bi];
            }
            #pragma unroll
            for (int fm = 0; fm < 4; fm++) {
                int arow = wm * 64 + fm * 16 + l15;
                int ai = arow * 16 + ((quad ^ swz(arow)) * 4);
                bf16x8 va = *(const bf16x8*)&Ah[half][ai];
                #pragma unroll
                for (int fn = 0; fn < 4; fn++)
                    acc[fm][fn] = __builtin_amdgcn_mfma_f32_16x16x32_bf16(vb[fn], va, acc[fm][fn], 0, 0, 0);
            }
        }
    }

    #pragma unroll
    for (int fm = 0; fm < 4; fm++) {
        int row = m0 + wm * 64 + fm * 16 + l15;
        #pragma unroll
        for (int fn = 0; fn < 4; fn++) {
            int colb = n0 + wn * 64 + fn * 16 + quad * 4;
            floatx4 a = acc[fm][fn];
            if (is_qv) {
                if (colb < 1024) {
                    uint32_t u0 = pack_bf16_rne(a[0], a[1]);
                    uint32_t u1 = pack_bf16_rne(a[2], a[3]);
                    size_t wi = (size_t)row * 512 + (colb >> 1);
                    *(uint2*)&qh[wi] = make_uint2(u0, u1);
                } else {
                    // V transposed: vt[h][d][token] bf16
                    int hh = (colb - 1024) >> 6;
                    int d0 = (colb - 1024) & 63;
                    #pragma unroll
                    for (int j = 0; j < 4; j++)
                        vt[(size_t)(hh * 64 + d0 + j) * 4096 + row] = bf16_rne1(a[j]);
                }
            } else {
                uint32_t u0 = pack_bf16_rne(a[0] * KSCALE, a[1] * KSCALE);
                uint32_t u1 = pack_bf16_rne(a[2] * KSCALE, a[3] * KSCALE);
                size_t wi = (size_t)row * 512 + (colb >> 1);
                *(uint2*)&kh[wi] = make_uint2(u0, u1);
            }
        }
    }
}

// ---------------- proj GEMM: bf16, split-K=2, BK=64, XCD swizzle ------------
__global__ __launch_bounds__(256, 3)
void gemm_projB(const uint32_t* __restrict__ Ag,
                const float* __restrict__ Bf, const float* __restrict__ bias,
                float* __restrict__ Cf, float* __restrict__ P1)
{
    __shared__ uint32_t Ah[2][128 * 16], Bh[2][128 * 16];

    const int t    = threadIdx.x;
    const int lane = t & 63;
    const int w    = t >> 6;
    const int wm   = w & 1, wn = w >> 1;
    const int quad = lane >> 4, l15 = lane & 15;

    // XCD-bijective block swizzle (512 % 8 == 0)
    const int lin = blockIdx.z * 256 + blockIdx.y * 8 + blockIdx.x;
    const int sl  = (lin & 7) * 64 + (lin >> 3);
    const int bxs = sl & 7;
    const int bys = (sl >> 3) & 31;
    const int kz  = sl >> 8;

    const int m0 = bys * 128, n0 = bxs * 128;
    const int k0 = kz * 512;
    const int N  = 1024;

    const int bc  = (t & 31) * 4;
    const int bk  = (t >> 5) * 4;
    const int bb  = bk >> 3;
    const int bp  = (bk & 7) >> 1;
    const bool nsel = ((bc >> 4) & 1) != 0;

    const int arow0 = t >> 2, akbl = t & 3;
    const int arow1 = (t + 256) >> 2;
    const int dst0 = arow0 * 16 + ((akbl ^ swz(arow0)) * 4);
    const int dst1 = arow1 * 16 + ((akbl ^ swz(arow1)) * 4);

    floatx4 acc[4][4];
    #pragma unroll
    for (int i = 0; i < 4; i++)
        #pragma unroll
        for (int j = 0; j < 4; j++)
            #pragma unroll
            for (int e = 0; e < 4; e++) acc[i][j][e] = 0.0f;

    uint4 gA00, gA01, gA10, gA11;
    float4 g40[4], g41[4];
    {
        size_t s0 = (size_t)(m0 + arow0) * 512 + (k0 >> 1) + akbl * 4;
        size_t s1 = (size_t)(m0 + arow1) * 512 + (k0 >> 1) + akbl * 4;
        gA00 = *(const uint4*)&Ag[s0];
        gA01 = *(const uint4*)&Ag[s1];
        gA10 = *(const uint4*)&Ag[s0 + 16];
        gA11 = *(const uint4*)&Ag[s1 + 16];
        #pragma unroll
        for (int j = 0; j < 4; j++) {
            g40[j] = *(const float4*)&Bf[(size_t)(k0 + bk + j) * N + n0 + bc];
            g41[j] = *(const float4*)&Bf[(size_t)(k0 + 32 + bk + j) * N + n0 + bc];
        }
    }

    for (int kk = 0; kk < 512; kk += 64) {
        if (kk) __syncthreads();
        {
            *(uint4*)&Ah[0][dst0] = gA00;
            *(uint4*)&Ah[0][dst1] = gA01;
            *(uint4*)&Ah[1][dst0] = gA10;
            *(uint4*)&Ah[1][dst1] = gA11;
        }
        {
            #pragma unroll
            for (int i = 0; i < 4; i++) {
                int n = bc + (i ^ (nsel ? 1 : 0));
                int bi = n * 16 + ((bb ^ swz(n)) * 4) + bp;
                float e0 = nsel ? ((const float*)&g40[0])[i ^ 1] : ((const float*)&g40[0])[i];
                float e1 = nsel ? ((const float*)&g40[1])[i ^ 1] : ((const float*)&g40[1])[i];
                float e2 = nsel ? ((const float*)&g40[2])[i ^ 1] : ((const float*)&g40[2])[i];
                float e3 = nsel ? ((const float*)&g40[3])[i ^ 1] : ((const float*)&g40[3])[i];
                *(uint2*)&Bh[0][bi] = make_uint2(pack_bf16_rne(e0, e1), pack_bf16_rne(e2, e3));
                e0 = nsel ? ((const float*)&g41[0])[i ^ 1] : ((const float*)&g41[0])[i];
                e1 = nsel ? ((const float*)&g41[1])[i ^ 1] : ((const float*)&g41[1])[i];
                e2 = nsel ? ((const float*)&g41[2])[i ^ 1] : ((const float*)&g41[2])[i];
                e3 = nsel ? ((const float*)&g41[3])[i ^ 1] : ((const float*)&g41[3])[i];
                *(uint2*)&Bh[1][bi] = make_uint2(pack_bf16_rne(e0, e1), pack_bf16_rne(e2, e3));
            }
        }
        __syncthreads();

        if (kk + 64 < 512) {
            const int kg = k0 + kk + 64;
            size_t s0 = (size_t)(m0 + arow0) * 512 + (kg >> 1) + akbl * 4;
            size_t s1 = (size_t)(m0 + arow1) * 512 + (kg >> 1) + akbl * 4;
            gA00 = *(const uint4*)&Ag[s0];
            gA01 = *(const uint4*)&Ag[s1];
            gA10 = *(const uint4*)&Ag[s0 + 16];
            gA11 = *(const uint4*)&Ag[s1 + 16];
            #pragma unroll
            for (int j = 0; j < 4; j++) {
                g40[j] = *(const float4*)&Bf[(size_t)(kg + bk + j) * N + n0 + bc];
                g41[j] = *(const float4*)&Bf[(size_t)(kg + 32 + bk + j) * N + n0 + bc];
            }
        }

        #pragma unroll
        for (int half = 0; half < 2; half++) {
            bf16x8 vb[4];
            #pragma unroll
            for (int fn = 0; fn < 4; fn++) {
                int br = wn * 64 + fn * 16 + l15;
                int bi = br * 16 + ((quad ^ swz(br)) * 4);
                vb[fn] = *(const bf16x8*)&Bh[half][bi];
            }
            #pragma unroll
            for (int fm = 0; fm < 4; fm++) {
                int arow = wm * 64 + fm * 16 + l15;
                int ai = arow * 16 + ((quad ^ swz(arow)) * 4);
                bf16x8 va = *(const bf16x8*)&Ah[half][ai];
                #pragma unroll
                for (int fn = 0; fn < 4; fn++)
                    acc[fm][fn] = __builtin_amdgcn_mfma_f32_16x16x32_bf16(vb[fn], va, acc[fm][fn], 0, 0, 0);
            }
        }
    }

    #pragma unroll
    for (int fm = 0; fm < 4; fm++) {
        int row = m0 + wm * 64 + fm * 16 + l15;
        #pragma unroll
        for (int fn = 0; fn < 4; fn++) {
            int colb = n0 + wn * 64 + fn * 16 + quad * 4;
            floatx4 a = acc[fm][fn];
            float4 v;
            if (kz == 0) {
                float4 bb4 = *(const float4*)&bias[colb];
                v.x = a[0] + bb4.x; v.y = a[1] + bb4.y;
                v.z = a[2] + bb4.z; v.w = a[3] + bb4.w;
                *(float4*)&Cf[(size_t)row * N + colb] = v;
            } else {
                v.x = a[0]; v.y = a[1]; v.z = a[2]; v.w = a[3];
                *(float4*)&P1[(size_t)row * N + colb] = v;
            }
        }
    }
}

// ---------------- combine: out += partial1 (L2/L3-resident) -----------------
__global__ __launch_bounds__(256)
void add_partial(const float4* __restrict__ p1, float4* __restrict__ out, int n4)
{
    int i = blockIdx.x * 256 + threadIdx.x;
    int stride = gridDim.x * 256;
    for (; i < n4; i += stride) {
        float4 a = out[i];
        float4 b = p1[i];
        a.x += b.x; a.y += b.y; a.z += b.z; a.w += b.w;
        out[i] = a;
    }
}

// ---------------- MFMA flash attention: KVBLK=128, V direct from L2 ---------
// R12's regression was the __launch_bounds__(256,3) VGPR cap (84 regs ->
// 180MB scratch spill), NOT the V-direct design. Bounds back to (256,2):
// compiler gets room (~112 regs, R11-like), LDS 51.2KB allows 3 blocks/CU.
#define FST 34   // Kh row stride (32 words + 2 pad)
#define FSP 66   // Pt row stride (64 words + 2 pad)
#define NT  (SEQ / 128)
__global__ __launch_bounds__(256, 2)
void flash_attn(const uint32_t* __restrict__ qhg,
                const uint32_t* __restrict__ khg,
                const uint32_t* __restrict__ vtg,
                uint32_t* __restrict__ xhg)
{
    __shared__ uint32_t Kh[128 * FST];   // 17.4 KB
    __shared__ uint32_t Pt[128 * FSP];   // 33.8 KB  -> 51.2 KB total

    const int t    = threadIdx.x;
    const int lane = t & 63;
    const int w    = t >> 6;
    const int quad = lane >> 4, l15 = lane & 15;
    const int qb = blockIdx.x;
    const int h  = blockIdx.y;
    const int b  = blockIdx.z;

    const size_t rowbase = (size_t)b * SEQ;

    // ---- Q fragments (bf16-rne): load once, keep in registers ----
    bf16x8 vq[2][2];     // [s][nf]
    {
        #pragma unroll
        for (int nf = 0; nf < 2; nf++) {
            size_t row = rowbase + qb * 128 + w * 32 + nf * 16 + l15;
            size_t gw = row * 512 + h * 32 + quad * 4;
            #pragma unroll
            for (int s = 0; s < 2; s++)
                vq[s][nf] = *(const bf16x8*)&qhg[gw + s * 16];
        }
    }

    // ---- K staging coords + tile kt=0 prefetch ----
    const int kr  = t >> 1, kc0 = (t & 1) * 16;
    uint4 pk0, pk1, pk2, pk3;
    {
        size_t gw = (rowbase + kr) * 512 + h * 32 + kc0;
        pk0 = *(const uint4*)&khg[gw];
        pk1 = *(const uint4*)&khg[gw + 4];
        pk2 = *(const uint4*)&khg[gw + 8];
        pk3 = *(const uint4*)&khg[gw + 12];
    }

    // ---- per-lane V base (direct global reads in PV) ----
    const size_t vbl = (size_t)(h * 64 + l15) * 2048 + (rowbase >> 1) + quad * 4;

    float m_i[2] = {-INFINITY, -INFINITY};
    float l_i[2] = {0.0f, 0.0f};
    floatx4 acc_o[2][4];
    #pragma unroll
    for (int nf = 0; nf < 2; nf++)
        #pragma unroll
        for (int fm = 0; fm < 4; fm++)
            #pragma unroll
            for (int e = 0; e < 4; e++) acc_o[nf][fm][e] = 0.0f;

    for (int kt = 0; kt < NT; kt++) {
        __syncthreads();
        // ---- stage K from registers (4x uint4) ----
        {
            int kb0 = kr * FST + kc0;
            *(uint4*)&Kh[kb0]      = pk0;
            *(uint4*)&Kh[kb0 + 4]  = pk1;
            *(uint4*)&Kh[kb0 + 8]  = pk2;
            *(uint4*)&Kh[kb0 + 12] = pk3;
        }
        __syncthreads();

        // ---- prefetch K tile kt+1 (completes during compute) ----
        if (kt + 1 < NT) {
            size_t gw = (rowbase + (kt + 1) * 128 + kr) * 512 + h * 32 + kc0;
            pk0 = *(const uint4*)&khg[gw];
            pk1 = *(const uint4*)&khg[gw + 4];
            pk2 = *(const uint4*)&khg[gw + 8];
            pk3 = *(const uint4*)&khg[gw + 12];
        }

        // ---- S^T = rne(K)·rne(Q): 32 MFMAs over 128 k-rows ----
        floatx4 sacc[2][8];
        #pragma unroll
        for (int nf = 0; nf < 2; nf++)
            #pragma unroll
            for (int fm = 0; fm < 8; fm++)
                #pragma unroll
                for (int e = 0; e < 4; e++) sacc[nf][fm][e] = 0.0f;

        __builtin_amdgcn_s_setprio(1);
        #pragma unroll
        for (int s = 0; s < 2; s++) {
            #pragma unroll
            for (int fm = 0; fm < 8; fm++) {
                int ki = (fm * 16 + l15) * FST + s * 16 + quad * 4;
                bf16x8 vk = *(const bf16x8*)&Kh[ki];
                #pragma unroll
                for (int nf = 0; nf < 2; nf++)
                    sacc[nf][fm] = __builtin_amdgcn_mfma_f32_16x16x32_bf16(vk, vq[s][nf], sacc[nf][fm], 0, 0, 0);
            }
        }
        __builtin_amdgcn_s_setprio(0);

        // ---- online softmax (in-place on sacc; defer-max THR=8) ----
        #pragma unroll
        for (int nf = 0; nf < 2; nf++) {
            float mt = -INFINITY;
            #pragma unroll
            for (int fm = 0; fm < 8; fm++)
                #pragma unroll
                for (int r = 0; r < 4; r++) mt = fmaxf(mt, sacc[nf][fm][r]);
            mt = fmaxf(mt, __shfl_xor(mt, 16));
            mt = fmaxf(mt, __shfl_xor(mt, 32));

            if (__all(mt - m_i[nf] <= 8.0f)) {
                float rs = 0.0f;
                #pragma unroll
                for (int fm = 0; fm < 8; fm++)
                    #pragma unroll
                    for (int r = 0; r < 4; r++) {
                        sacc[nf][fm][r] = EXP2(sacc[nf][fm][r] - m_i[nf]);
                        rs += sacc[nf][fm][r];
                    }
                rs += __shfl_xor(rs, 16);
                rs += __shfl_xor(rs, 32);
                l_i[nf] += rs;
            } else {
                float m_new = fmaxf(m_i[nf], mt);
                float alpha = EXP2(m_i[nf] - m_new);
                float rs = 0.0f;
                #pragma unroll
                for (int fm = 0; fm < 8; fm++)
                    #pragma unroll
                    for (int r = 0; r < 4; r++) {
                        sacc[nf][fm][r] = EXP2(sacc[nf][fm][r] - m_new);
                        rs += sacc[nf][fm][r];
                    }
                rs += __shfl_xor(rs, 16);
                rs += __shfl_xor(rs, 32);
                l_i[nf] = l_i[nf] * alpha + rs;
                m_i[nf] = m_new;
                #pragma unroll
                for (int fm = 0; fm < 4; fm++)
                    #pragma unroll
                    for (int e = 0; e < 4; e++) acc_o[nf][fm][e] *= alpha;
            }

            int qrow = w * 32 + nf * 16 + l15;
            #pragma unroll
            for (int fm = 0; fm < 8; fm++) {
                uint32_t u0 = pack_bf16_rne(sacc[nf][fm][0], sacc[nf][fm][1]);
                uint32_t u1 = pack_bf16_rne(sacc[nf][fm][2], sacc[nf][fm][3]);
                *(uint2*)&Pt[qrow * FSP + fm * 8 + quad * 2] = make_uint2(u0, u1);
            }
        }

        // ---- O^T += V · P^T (V fragments direct from global/L2) ----
        __builtin_amdgcn_s_setprio(1);
        #pragma unroll
        for (int s = 0; s < 4; s++) {
            bf16x8 pb[2];
            #pragma unroll
            for (int nf = 0; nf < 2; nf++)
                pb[nf] = *(const bf16x8*)&Pt[(w * 32 + nf * 16 + l15) * FSP + s * 16 + quad * 4];
            #pragma unroll
            for (int fm = 0; fm < 4; fm++) {
                bf16x8 va = *(const bf16x8*)&vtg[vbl + (size_t)fm * 32768 + kt * 64 + s * 16];
                #pragma unroll
                for (int nf = 0; nf < 2; nf++)
                    acc_o[nf][fm] = __builtin_amdgcn_mfma_f32_16x16x32_bf16(va, pb[nf], acc_o[nf][fm], 0, 0, 0);
            }
        }
        __builtin_amdgcn_s_setprio(0);
    }

    // ---- epilogue: write x single bf16-rne ----
    #pragma unroll
    for (int nf = 0; nf < 2; nf++) {
        float rl = 1.0f / l_i[nf];
        size_t row = rowbase + qb * 128 + w * 32 + nf * 16 + l15;
        #pragma unroll
        for (int fm = 0; fm < 4; fm++) {
            int d0 = fm * 16 + quad * 4;
            uint32_t u0 = pack_bf16_rne(acc_o[nf][fm][0] * rl, acc_o[nf][fm][1] * rl);
            uint32_t u1 = pack_bf16_rne(acc_o[nf][fm][2] * rl, acc_o[nf][fm][3] * rl);
            size_t wi = row * 512 + ((h * 64 + d0) >> 1);
            *(uint2*)&xhg[wi] = make_uint2(u0, u1);
        }
    }
}

extern "C" void kernel_launch(void* const* d_in, const int* in_sizes, int n_in,
                              void* d_out, int out_size, void* d_ws, size_t ws_size,
                              hipStream_t stream)
{
    const float* input_qv = (const float*)d_in[0];
    const float* input_k  = (const float*)d_in[1];
    const float* W_qv     = (const float*)d_in[2];
    const float* W_k      = (const float*)d_in[3];
    const float* W_proj   = (const float*)d_in[4];
    const float* b_proj   = (const float*)d_in[5];
    float* out = (float*)d_out;

    const size_t RW = 4096 * 512;            // words per [4096][1024-bf16] buffer
    uint32_t* qh = (uint32_t*)d_ws;          // 3 RW = 25.2 MB total
    uint32_t* vt = qh + RW;                  // V^T [16 h][64 d][4096 tok] bf16
    uint32_t* xh = vt + RW;                  // attention out, single bf16
    uint32_t* kh = (uint32_t*)d_out;         // rne K parked in d_out (8.4 MB);
                                             // proj GEMM rewrites out afterwards
    float* p1 = (float*)d_ws;                // split-K partial: aliases qh+vt
                                             // (dead after flash_attn), 16.8 MB

    dim3 blk(256);
    // fused qv+k projections: 768 blocks, XCD-swizzled
    gemm_qvk<<<dim3(24, 32), blk, 0, stream>>>(
        input_qv, input_k, W_qv, W_k, qh, (ushort*)vt, kh);
    // flash attention: KVBLK=128, V direct from L2, proper reg budget
    flash_attn<<<dim3(SEQ / 128, NH, BATCH), blk, 0, stream>>>(
        qh, kh, vt, xh);
    // output projection + bias: bf16, split-K=2, XCD-swizzled
    gemm_projB<<<dim3(8, 32, 2), blk, 0, stream>>>(
        xh, W_proj, b_proj, out, p1);
    // out += partial1
    add_partial<<<dim3(2048), blk, 0, stream>>>(
        (const float4*)p1, (float4*)out, 4096 * 1024 / 4);
}

// Round 14
// 240.048 us; speedup vs baseline: 1.3223x; 1.0836x over previous
//
#include <hip/hip_runtime.h>
#include <stdint.h>

#define BATCH 2
#define SEQ   2048
#define DIM   1024
#define NH    16
#define DH    64

typedef short bf16x8 __attribute__((ext_vector_type(8)));
typedef float floatx4 __attribute__((ext_vector_type(4)));

__device__ __forceinline__ int swz(int r) { return (r ^ (r >> 2)) & 3; }

// fast 2^x: raw v_exp_f32
#if __has_builtin(__builtin_amdgcn_exp2f)
#define EXP2(x) __builtin_amdgcn_exp2f(x)
#else
#define EXP2(x) __expf((x) * 0.6931471805599453f)
#endif

__device__ __forceinline__ uint32_t pack_bf16_rne(float x0, float x1) {
    uint32_t u0 = __float_as_uint(x0), u1 = __float_as_uint(x1);
    u0 += 0x7FFFu + ((u0 >> 16) & 1);
    u1 += 0x7FFFu + ((u1 >> 16) & 1);
    return (u0 >> 16) | (u1 & 0xFFFF0000u);
}

__device__ __forceinline__ ushort bf16_rne1(float x) {
    uint32_t u = __float_as_uint(x);
    u += 0x7FFFu + ((u >> 16) & 1);
    return (ushort)(u >> 16);
}

// softmax scale folded into K: 0.125 * log2(e) -> flash uses exp2
#define KSCALE 0.18033688011112042f

// ---------------- fused qv+k projection GEMM: bf16, BK=64, XCD swizzle ------
__global__ __launch_bounds__(256, 3)
void gemm_qvk(const float* __restrict__ Aqv, const float* __restrict__ Akp,
              const float* __restrict__ Wqv, const float* __restrict__ Wkp,
              uint32_t* __restrict__ qh, ushort* __restrict__ vt,
              uint32_t* __restrict__ kh)
{
    __shared__ uint32_t Ah[2][128 * 16], Bh[2][128 * 16];

    const int t    = threadIdx.x;
    const int lane = t & 63;
    const int w    = t >> 6;
    const int wm   = w & 1, wn = w >> 1;
    const int quad = lane >> 4, l15 = lane & 15;

    // XCD-bijective block swizzle (768 % 8 == 0)
    const int lin = blockIdx.y * 24 + blockIdx.x;
    const int sl  = (lin & 7) * 96 + (lin >> 3);
    const int bxs = sl % 24;
    const int bys = sl / 24;

    const bool is_qv = (bxs < 16);
    const float* Af = is_qv ? Aqv : Akp;
    const float* Bf = is_qv ? Wqv : Wkp;
    const int N    = is_qv ? 2048 : 1024;
    const int n0   = (is_qv ? bxs : bxs - 16) * 128;
    const int m0   = bys * 128;

    const int ar  = t >> 1;
    const int ab0 = (t & 1) * 2;
    const int as  = swz(ar);
    const int bc  = (t & 31) * 4;
    const int bk  = (t >> 5) * 4;
    const int bb  = bk >> 3;
    const int bp  = (bk & 7) >> 1;
    const bool nsel = ((bc >> 4) & 1) != 0;

    floatx4 acc[4][4];
    #pragma unroll
    for (int i = 0; i < 4; i++)
        #pragma unroll
        for (int j = 0; j < 4; j++)
            #pragma unroll
            for (int e = 0; e < 4; e++) acc[i][j][e] = 0.0f;

    // prefetch registers, static indexing only (scratch hazard otherwise)
    float f0[16], f1[16];
    float4 g40[4], g41[4];
    {
        #pragma unroll
        for (int i = 0; i < 4; i++) {
            *(float4*)&f0[i * 4] =
                *(const float4*)&Af[(size_t)(m0 + ar) * 1024 + ab0 * 8 + i * 4];
            *(float4*)&f1[i * 4] =
                *(const float4*)&Af[(size_t)(m0 + ar) * 1024 + 32 + ab0 * 8 + i * 4];
        }
        #pragma unroll
        for (int j = 0; j < 4; j++) {
            g40[j] = *(const float4*)&Bf[(size_t)(bk + j) * N + n0 + bc];
            g41[j] = *(const float4*)&Bf[(size_t)(32 + bk + j) * N + n0 + bc];
        }
    }

    for (int k0 = 0; k0 < 1024; k0 += 64) {
        if (k0) __syncthreads();
        // ---- stage A halves (bf16-rne pack) ----
        {
            uint32_t hi[8];
            #pragma unroll
            for (int j = 0; j < 8; j++) hi[j] = pack_bf16_rne(f0[2 * j], f0[2 * j + 1]);
            int i0 = ar * 16 + ((ab0 ^ as) * 4);
            int i1 = ar * 16 + (((ab0 + 1) ^ as) * 4);
            *(uint4*)&Ah[0][i0] = make_uint4(hi[0], hi[1], hi[2], hi[3]);
            *(uint4*)&Ah[0][i1] = make_uint4(hi[4], hi[5], hi[6], hi[7]);
            #pragma unroll
            for (int j = 0; j < 8; j++) hi[j] = pack_bf16_rne(f1[2 * j], f1[2 * j + 1]);
            *(uint4*)&Ah[1][i0] = make_uint4(hi[0], hi[1], hi[2], hi[3]);
            *(uint4*)&Ah[1][i1] = make_uint4(hi[4], hi[5], hi[6], hi[7]);
        }
        // ---- stage B halves (conflict-min order, static extracts) ----
        {
            #pragma unroll
            for (int i = 0; i < 4; i++) {
                int n = bc + (i ^ (nsel ? 1 : 0));
                int bi = n * 16 + ((bb ^ swz(n)) * 4) + bp;
                float e0 = nsel ? ((const float*)&g40[0])[i ^ 1] : ((const float*)&g40[0])[i];
                float e1 = nsel ? ((const float*)&g40[1])[i ^ 1] : ((const float*)&g40[1])[i];
                float e2 = nsel ? ((const float*)&g40[2])[i ^ 1] : ((const float*)&g40[2])[i];
                float e3 = nsel ? ((const float*)&g40[3])[i ^ 1] : ((const float*)&g40[3])[i];
                *(uint2*)&Bh[0][bi] = make_uint2(pack_bf16_rne(e0, e1), pack_bf16_rne(e2, e3));
                e0 = nsel ? ((const float*)&g41[0])[i ^ 1] : ((const float*)&g41[0])[i];
                e1 = nsel ? ((const float*)&g41[1])[i ^ 1] : ((const float*)&g41[1])[i];
                e2 = nsel ? ((const float*)&g41[2])[i ^ 1] : ((const float*)&g41[2])[i];
                e3 = nsel ? ((const float*)&g41[3])[i ^ 1] : ((const float*)&g41[3])[i];
                *(uint2*)&Bh[1][bi] = make_uint2(pack_bf16_rne(e0, e1), pack_bf16_rne(e2, e3));
            }
        }
        __syncthreads();

        // ---- prefetch next BK=64 step ----
        if (k0 + 64 < 1024) {
            #pragma unroll
            for (int i = 0; i < 4; i++) {
                *(float4*)&f0[i * 4] =
                    *(const float4*)&Af[(size_t)(m0 + ar) * 1024 + (k0 + 64) + ab0 * 8 + i * 4];
                *(float4*)&f1[i * 4] =
                    *(const float4*)&Af[(size_t)(m0 + ar) * 1024 + (k0 + 96) + ab0 * 8 + i * 4];
            }
            #pragma unroll
            for (int j = 0; j < 4; j++) {
                g40[j] = *(const float4*)&Bf[(size_t)(k0 + 64 + bk + j) * N + n0 + bc];
                g41[j] = *(const float4*)&Bf[(size_t)(k0 + 96 + bk + j) * N + n0 + bc];
            }
        }

        #pragma unroll
        for (int half = 0; half < 2; half++) {
            bf16x8 vb[4];
            #pragma unroll
            for (int fn = 0; fn < 4; fn++) {
                int br = wn * 64 + fn * 16 + l15;
                int bi = br * 16 + ((quad ^ swz(br)) * 4);
                vb[fn] = *(const bf16x8*)&Bh[half][bi];
            }
            #pragma unroll
            for (int fm = 0; fm < 4; fm++) {
                int arow = wm * 64 + fm * 16 + l15;
                int ai = arow * 16 + ((quad ^ swz(arow)) * 4);
                bf16x8 va = *(const bf16x8*)&Ah[half][ai];
                #pragma unroll
                for (int fn = 0; fn < 4; fn++)
                    acc[fm][fn] = __builtin_amdgcn_mfma_f32_16x16x32_bf16(vb[fn], va, acc[fm][fn], 0, 0, 0);
            }
        }
    }

    #pragma unroll
    for (int fm = 0; fm < 4; fm++) {
        int row = m0 + wm * 64 + fm * 16 + l15;
        #pragma unroll
        for (int fn = 0; fn < 4; fn++) {
            int colb = n0 + wn * 64 + fn * 16 + quad * 4;
            floatx4 a = acc[fm][fn];
            if (is_qv) {
                if (colb < 1024) {
                    uint32_t u0 = pack_bf16_rne(a[0], a[1]);
                    uint32_t u1 = pack_bf16_rne(a[2], a[3]);
                    size_t wi = (size_t)row * 512 + (colb >> 1);
                    *(uint2*)&qh[wi] = make_uint2(u0, u1);
                } else {
                    // V transposed: vt[h][d][token] bf16
                    int hh = (colb - 1024) >> 6;
                    int d0 = (colb - 1024) & 63;
                    #pragma unroll
                    for (int j = 0; j < 4; j++)
                        vt[(size_t)(hh * 64 + d0 + j) * 4096 + row] = bf16_rne1(a[j]);
                }
            } else {
                uint32_t u0 = pack_bf16_rne(a[0] * KSCALE, a[1] * KSCALE);
                uint32_t u1 = pack_bf16_rne(a[2] * KSCALE, a[3] * KSCALE);
                size_t wi = (size_t)row * 512 + (colb >> 1);
                *(uint2*)&kh[wi] = make_uint2(u0, u1);
            }
        }
    }
}

// ---------------- proj GEMM: bf16, split-K=2, BK=64, XCD swizzle ------------
__global__ __launch_bounds__(256, 3)
void gemm_projB(const uint32_t* __restrict__ Ag,
                const float* __restrict__ Bf, const float* __restrict__ bias,
                float* __restrict__ Cf, float* __restrict__ P1)
{
    __shared__ uint32_t Ah[2][128 * 16], Bh[2][128 * 16];

    const int t    = threadIdx.x;
    const int lane = t & 63;
    const int w    = t >> 6;
    const int wm   = w & 1, wn = w >> 1;
    const int quad = lane >> 4, l15 = lane & 15;

    // XCD-bijective block swizzle (512 % 8 == 0)
    const int lin = blockIdx.z * 256 + blockIdx.y * 8 + blockIdx.x;
    const int sl  = (lin & 7) * 64 + (lin >> 3);
    const int bxs = sl & 7;
    const int bys = (sl >> 3) & 31;
    const int kz  = sl >> 8;

    const int m0 = bys * 128, n0 = bxs * 128;
    const int k0 = kz * 512;
    const int N  = 1024;

    const int bc  = (t & 31) * 4;
    const int bk  = (t >> 5) * 4;
    const int bb  = bk >> 3;
    const int bp  = (bk & 7) >> 1;
    const bool nsel = ((bc >> 4) & 1) != 0;

    const int arow0 = t >> 2, akbl = t & 3;
    const int arow1 = (t + 256) >> 2;
    const int dst0 = arow0 * 16 + ((akbl ^ swz(arow0)) * 4);
    const int dst1 = arow1 * 16 + ((akbl ^ swz(arow1)) * 4);

    floatx4 acc[4][4];
    #pragma unroll
    for (int i = 0; i < 4; i++)
        #pragma unroll
        for (int j = 0; j < 4; j++)
            #pragma unroll
            for (int e = 0; e < 4; e++) acc[i][j][e] = 0.0f;

    uint4 gA00, gA01, gA10, gA11;
    float4 g40[4], g41[4];
    {
        size_t s0 = (size_t)(m0 + arow0) * 512 + (k0 >> 1) + akbl * 4;
        size_t s1 = (size_t)(m0 + arow1) * 512 + (k0 >> 1) + akbl * 4;
        gA00 = *(const uint4*)&Ag[s0];
        gA01 = *(const uint4*)&Ag[s1];
        gA10 = *(const uint4*)&Ag[s0 + 16];
        gA11 = *(const uint4*)&Ag[s1 + 16];
        #pragma unroll
        for (int j = 0; j < 4; j++) {
            g40[j] = *(const float4*)&Bf[(size_t)(k0 + bk + j) * N + n0 + bc];
            g41[j] = *(const float4*)&Bf[(size_t)(k0 + 32 + bk + j) * N + n0 + bc];
        }
    }

    for (int kk = 0; kk < 512; kk += 64) {
        if (kk) __syncthreads();
        {
            *(uint4*)&Ah[0][dst0] = gA00;
            *(uint4*)&Ah[0][dst1] = gA01;
            *(uint4*)&Ah[1][dst0] = gA10;
            *(uint4*)&Ah[1][dst1] = gA11;
        }
        {
            #pragma unroll
            for (int i = 0; i < 4; i++) {
                int n = bc + (i ^ (nsel ? 1 : 0));
                int bi = n * 16 + ((bb ^ swz(n)) * 4) + bp;
                float e0 = nsel ? ((const float*)&g40[0])[i ^ 1] : ((const float*)&g40[0])[i];
                float e1 = nsel ? ((const float*)&g40[1])[i ^ 1] : ((const float*)&g40[1])[i];
                float e2 = nsel ? ((const float*)&g40[2])[i ^ 1] : ((const float*)&g40[2])[i];
                float e3 = nsel ? ((const float*)&g40[3])[i ^ 1] : ((const float*)&g40[3])[i];
                *(uint2*)&Bh[0][bi] = make_uint2(pack_bf16_rne(e0, e1), pack_bf16_rne(e2, e3));
                e0 = nsel ? ((const float*)&g41[0])[i ^ 1] : ((const float*)&g41[0])[i];
                e1 = nsel ? ((const float*)&g41[1])[i ^ 1] : ((const float*)&g41[1])[i];
                e2 = nsel ? ((const float*)&g41[2])[i ^ 1] : ((const float*)&g41[2])[i];
                e3 = nsel ? ((const float*)&g41[3])[i ^ 1] : ((const float*)&g41[3])[i];
                *(uint2*)&Bh[1][bi] = make_uint2(pack_bf16_rne(e0, e1), pack_bf16_rne(e2, e3));
            }
        }
        __syncthreads();

        if (kk + 64 < 512) {
            const int kg = k0 + kk + 64;
            size_t s0 = (size_t)(m0 + arow0) * 512 + (kg >> 1) + akbl * 4;
            size_t s1 = (size_t)(m0 + arow1) * 512 + (kg >> 1) + akbl * 4;
            gA00 = *(const uint4*)&Ag[s0];
            gA01 = *(const uint4*)&Ag[s1];
            gA10 = *(const uint4*)&Ag[s0 + 16];
            gA11 = *(const uint4*)&Ag[s1 + 16];
            #pragma unroll
            for (int j = 0; j < 4; j++) {
                g40[j] = *(const float4*)&Bf[(size_t)(kg + bk + j) * N + n0 + bc];
                g41[j] = *(const float4*)&Bf[(size_t)(kg + 32 + bk + j) * N + n0 + bc];
            }
        }

        #pragma unroll
        for (int half = 0; half < 2; half++) {
            bf16x8 vb[4];
            #pragma unroll
            for (int fn = 0; fn < 4; fn++) {
                int br = wn * 64 + fn * 16 + l15;
                int bi = br * 16 + ((quad ^ swz(br)) * 4);
                vb[fn] = *(const bf16x8*)&Bh[half][bi];
            }
            #pragma unroll
            for (int fm = 0; fm < 4; fm++) {
                int arow = wm * 64 + fm * 16 + l15;
                int ai = arow * 16 + ((quad ^ swz(arow)) * 4);
                bf16x8 va = *(const bf16x8*)&Ah[half][ai];
                #pragma unroll
                for (int fn = 0; fn < 4; fn++)
                    acc[fm][fn] = __builtin_amdgcn_mfma_f32_16x16x32_bf16(vb[fn], va, acc[fm][fn], 0, 0, 0);
            }
        }
    }

    #pragma unroll
    for (int fm = 0; fm < 4; fm++) {
        int row = m0 + wm * 64 + fm * 16 + l15;
        #pragma unroll
        for (int fn = 0; fn < 4; fn++) {
            int colb = n0 + wn * 64 + fn * 16 + quad * 4;
            floatx4 a = acc[fm][fn];
            float4 v;
            if (kz == 0) {
                float4 bb4 = *(const float4*)&bias[colb];
                v.x = a[0] + bb4.x; v.y = a[1] + bb4.y;
                v.z = a[2] + bb4.z; v.w = a[3] + bb4.w;
                *(float4*)&Cf[(size_t)row * N + colb] = v;
            } else {
                v.x = a[0]; v.y = a[1]; v.z = a[2]; v.w = a[3];
                *(float4*)&P1[(size_t)row * N + colb] = v;
            }
        }
    }
}

// ---------------- combine: out += partial1 (L2/L3-resident) -----------------
__global__ __launch_bounds__(256)
void add_partial(const float4* __restrict__ p1, float4* __restrict__ out, int n4)
{
    int i = blockIdx.x * 256 + threadIdx.x;
    int stride = gridDim.x * 256;
    for (; i < n4; i += stride) {
        float4 a = out[i];
        float4 b = p1[i];
        a.x += b.x; a.y += b.y; a.z += b.z; a.w += b.w;
        out[i] = a;
    }
}

// ---------------- MFMA flash attention: R11-proven (KVBLK=128, staged Vt) ---
// R13 refuted V-direct-from-L2 (96us vs 74us staged): the 16 V loads/iter
// sit on the PV critical path and expose serial L2 latency; LDS staging is
// the prefetch vehicle. This is the R11 kernel verbatim (measured 74.1us).
#define FST 34   // Kh row stride (32 words + 2 pad)
#define FSV 66   // Vt row stride (64 words + 2 pad)
#define FSP 66   // Pt row stride
#define NT  (SEQ / 128)
__global__ __launch_bounds__(256, 2)
void flash_attn(const uint32_t* __restrict__ qhg,
                const uint32_t* __restrict__ khg,
                const uint32_t* __restrict__ vtg,
                uint32_t* __restrict__ xhg)
{
    __shared__ uint32_t Kh[128 * FST];   // 17.4 KB
    __shared__ uint32_t Vt[64 * FSV];    // 16.9 KB
    __shared__ uint32_t Pt[128 * FSP];   // 33.8 KB  -> 68.1 KB total, 2/CU

    const int t    = threadIdx.x;
    const int lane = t & 63;
    const int w    = t >> 6;
    const int quad = lane >> 4, l15 = lane & 15;
    const int qb = blockIdx.x;
    const int h  = blockIdx.y;
    const int b  = blockIdx.z;

    const size_t rowbase = (size_t)b * SEQ;

    // ---- Q fragments (bf16-rne): load once, keep in registers ----
    bf16x8 vq[2][2];     // [s][nf]
    {
        #pragma unroll
        for (int nf = 0; nf < 2; nf++) {
            size_t row = rowbase + qb * 128 + w * 32 + nf * 16 + l15;
            size_t gw = row * 512 + h * 32 + quad * 4;
            #pragma unroll
            for (int s = 0; s < 2; s++)
                vq[s][nf] = *(const bf16x8*)&qhg[gw + s * 16];
        }
    }

    // ---- staging coords + tile kt=0 prefetch ----
    const int kr  = t >> 1, kc0 = (t & 1) * 16;
    const int vd = t >> 2, vc = t & 3;
    const size_t vrow = (size_t)(h * 64 + vd) * 2048 + (rowbase >> 1);
    uint4 pk0, pk1, pk2, pk3, pv0, pv1, pv2, pv3;
    {
        size_t gw = (rowbase + kr) * 512 + h * 32 + kc0;
        pk0 = *(const uint4*)&khg[gw];
        pk1 = *(const uint4*)&khg[gw + 4];
        pk2 = *(const uint4*)&khg[gw + 8];
        pk3 = *(const uint4*)&khg[gw + 12];
        size_t vw = vrow + vc * 16;
        pv0 = *(const uint4*)&vtg[vw];
        pv1 = *(const uint4*)&vtg[vw + 4];
        pv2 = *(const uint4*)&vtg[vw + 8];
        pv3 = *(const uint4*)&vtg[vw + 12];
    }

    float m_i[2] = {-INFINITY, -INFINITY};
    float l_i[2] = {0.0f, 0.0f};
    floatx4 acc_o[2][4];
    #pragma unroll
    for (int nf = 0; nf < 2; nf++)
        #pragma unroll
        for (int fm = 0; fm < 4; fm++)
            #pragma unroll
            for (int e = 0; e < 4; e++) acc_o[nf][fm][e] = 0.0f;

    for (int kt = 0; kt < NT; kt++) {
        __syncthreads();
        // ---- stage K from registers (4x uint4) ----
        {
            int kb0 = kr * FST + kc0;
            *(uint4*)&Kh[kb0]      = pk0;
            *(uint4*)&Kh[kb0 + 4]  = pk1;
            *(uint4*)&Kh[kb0 + 8]  = pk2;
            *(uint4*)&Kh[kb0 + 12] = pk3;
        }
        // ---- stage V^T from registers (8x uint2) ----
        {
            int vb0 = vd * FSV + vc * 16;
            *(uint2*)&Vt[vb0]      = make_uint2(pv0.x, pv0.y);
            *(uint2*)&Vt[vb0 + 2]  = make_uint2(pv0.z, pv0.w);
            *(uint2*)&Vt[vb0 + 4]  = make_uint2(pv1.x, pv1.y);
            *(uint2*)&Vt[vb0 + 6]  = make_uint2(pv1.z, pv1.w);
            *(uint2*)&Vt[vb0 + 8]  = make_uint2(pv2.x, pv2.y);
            *(uint2*)&Vt[vb0 + 10] = make_uint2(pv2.z, pv2.w);
            *(uint2*)&Vt[vb0 + 12] = make_uint2(pv3.x, pv3.y);
            *(uint2*)&Vt[vb0 + 14] = make_uint2(pv3.z, pv3.w);
        }
        __syncthreads();

        // ---- prefetch tile kt+1 (completes during compute) ----
        if (kt + 1 < NT) {
            size_t gw = (rowbase + (kt + 1) * 128 + kr) * 512 + h * 32 + kc0;
            pk0 = *(const uint4*)&khg[gw];
            pk1 = *(const uint4*)&khg[gw + 4];
            pk2 = *(const uint4*)&khg[gw + 8];
            pk3 = *(const uint4*)&khg[gw + 12];
            size_t vw = vrow + (kt + 1) * 64 + vc * 16;
            pv0 = *(const uint4*)&vtg[vw];
            pv1 = *(const uint4*)&vtg[vw + 4];
            pv2 = *(const uint4*)&vtg[vw + 8];
            pv3 = *(const uint4*)&vtg[vw + 12];
        }

        // ---- S^T = rne(K)·rne(Q): 32 MFMAs over 128 k-rows ----
        floatx4 sacc[2][8];
        #pragma unroll
        for (int nf = 0; nf < 2; nf++)
            #pragma unroll
            for (int fm = 0; fm < 8; fm++)
                #pragma unroll
                for (int e = 0; e < 4; e++) sacc[nf][fm][e] = 0.0f;

        __builtin_amdgcn_s_setprio(1);
        #pragma unroll
        for (int s = 0; s < 2; s++) {
            #pragma unroll
            for (int fm = 0; fm < 8; fm++) {
                int ki = (fm * 16 + l15) * FST + s * 16 + quad * 4;
                bf16x8 vk = *(const bf16x8*)&Kh[ki];
                #pragma unroll
                for (int nf = 0; nf < 2; nf++)
                    sacc[nf][fm] = __builtin_amdgcn_mfma_f32_16x16x32_bf16(vk, vq[s][nf], sacc[nf][fm], 0, 0, 0);
            }
        }
        __builtin_amdgcn_s_setprio(0);

        // ---- online softmax (in-place on sacc; defer-max THR=8) ----
        #pragma unroll
        for (int nf = 0; nf < 2; nf++) {
            float mt = -INFINITY;
            #pragma unroll
            for (int fm = 0; fm < 8; fm++)
                #pragma unroll
                for (int r = 0; r < 4; r++) mt = fmaxf(mt, sacc[nf][fm][r]);
            mt = fmaxf(mt, __shfl_xor(mt, 16));
            mt = fmaxf(mt, __shfl_xor(mt, 32));

            if (__all(mt - m_i[nf] <= 8.0f)) {
                float rs = 0.0f;
                #pragma unroll
                for (int fm = 0; fm < 8; fm++)
                    #pragma unroll
                    for (int r = 0; r < 4; r++) {
                        sacc[nf][fm][r] = EXP2(sacc[nf][fm][r] - m_i[nf]);
                        rs += sacc[nf][fm][r];
                    }
                rs += __shfl_xor(rs, 16);
                rs += __shfl_xor(rs, 32);
                l_i[nf] += rs;
            } else {
                float m_new = fmaxf(m_i[nf], mt);
                float alpha = EXP2(m_i[nf] - m_new);
                float rs = 0.0f;
                #pragma unroll
                for (int fm = 0; fm < 8; fm++)
                    #pragma unroll
                    for (int r = 0; r < 4; r++) {
                        sacc[nf][fm][r] = EXP2(sacc[nf][fm][r] - m_new);
                        rs += sacc[nf][fm][r];
                    }
                rs += __shfl_xor(rs, 16);
                rs += __shfl_xor(rs, 32);
                l_i[nf] = l_i[nf] * alpha + rs;
                m_i[nf] = m_new;
                #pragma unroll
                for (int fm = 0; fm < 4; fm++)
                    #pragma unroll
                    for (int e = 0; e < 4; e++) acc_o[nf][fm][e] *= alpha;
            }

            int qrow = w * 32 + nf * 16 + l15;
            #pragma unroll
            for (int fm = 0; fm < 8; fm++) {
                uint32_t u0 = pack_bf16_rne(sacc[nf][fm][0], sacc[nf][fm][1]);
                uint32_t u1 = pack_bf16_rne(sacc[nf][fm][2], sacc[nf][fm][3]);
                *(uint2*)&Pt[qrow * FSP + fm * 8 + quad * 2] = make_uint2(u0, u1);
            }
        }

        // ---- O^T += Vt · P^T (contraction over 128 k, s=0..3) ----
        __builtin_amdgcn_s_setprio(1);
        #pragma unroll
        for (int s = 0; s < 4; s++) {
            bf16x8 pb[2];
            #pragma unroll
            for (int nf = 0; nf < 2; nf++)
                pb[nf] = *(const bf16x8*)&Pt[(w * 32 + nf * 16 + l15) * FSP + s * 16 + quad * 4];
            #pragma unroll
            for (int fm = 0; fm < 4; fm++) {
                bf16x8 va = *(const bf16x8*)&Vt[(fm * 16 + l15) * FSV + s * 16 + quad * 4];
                #pragma unroll
                for (int nf = 0; nf < 2; nf++)
                    acc_o[nf][fm] = __builtin_amdgcn_mfma_f32_16x16x32_bf16(va, pb[nf], acc_o[nf][fm], 0, 0, 0);
            }
        }
        __builtin_amdgcn_s_setprio(0);
    }

    // ---- epilogue: write x single bf16-rne ----
    #pragma unroll
    for (int nf = 0; nf < 2; nf++) {
        float rl = 1.0f / l_i[nf];
        size_t row = rowbase + qb * 128 + w * 32 + nf * 16 + l15;
        #pragma unroll
        for (int fm = 0; fm < 4; fm++) {
            int d0 = fm * 16 + quad * 4;
            uint32_t u0 = pack_bf16_rne(acc_o[nf][fm][0] * rl, acc_o[nf][fm][1] * rl);
            uint32_t u1 = pack_bf16_rne(acc_o[nf][fm][2] * rl, acc_o[nf][fm][3] * rl);
            size_t wi = row * 512 + ((h * 64 + d0) >> 1);
            *(uint2*)&xhg[wi] = make_uint2(u0, u1);
        }
    }
}

extern "C" void kernel_launch(void* const* d_in, const int* in_sizes, int n_in,
                              void* d_out, int out_size, void* d_ws, size_t ws_size,
                              hipStream_t stream)
{
    const float* input_qv = (const float*)d_in[0];
    const float* input_k  = (const float*)d_in[1];
    const float* W_qv     = (const float*)d_in[2];
    const float* W_k      = (const float*)d_in[3];
    const float* W_proj   = (const float*)d_in[4];
    const float* b_proj   = (const float*)d_in[5];
    float* out = (float*)d_out;

    const size_t RW = 4096 * 512;            // words per [4096][1024-bf16] buffer
    uint32_t* qh = (uint32_t*)d_ws;          // 3 RW = 25.2 MB total
    uint32_t* vt = qh + RW;                  // V^T [16 h][64 d][4096 tok] bf16
    uint32_t* xh = vt + RW;                  // attention out, single bf16
    uint32_t* kh = (uint32_t*)d_out;         // rne K parked in d_out (8.4 MB);
                                             // proj GEMM rewrites out afterwards
    float* p1 = (float*)d_ws;                // split-K partial: aliases qh+vt
                                             // (dead after flash_attn), 16.8 MB

    dim3 blk(256);
    // fused qv+k projections: 768 blocks, XCD-swizzled
    gemm_qvk<<<dim3(24, 32), blk, 0, stream>>>(
        input_qv, input_k, W_qv, W_k, qh, (ushort*)vt, kh);
    // flash attention: R11-proven staged-Vt KVBLK=128
    flash_attn<<<dim3(SEQ / 128, NH, BATCH), blk, 0, stream>>>(
        qh, kh, vt, xh);
    // output projection + bias: bf16, split-K=2, XCD-swizzled
    gemm_projB<<<dim3(8, 32, 2), blk, 0, stream>>>(
        xh, W_proj, b_proj, out, p1);
    // out += partial1
    add_partial<<<dim3(2048), blk, 0, stream>>>(
        (const float4*)p1, (float4*)out, 4096 * 1024 / 4);
}